// Round 10
// baseline (129.692 us; speedup 1.0000x reference)
//
#include <hip/hip_runtime.h>
#include <hip/hip_fp16.h>

// DCNv2 R10: 32-px blocks for 2x chain concurrency in k_fused.
//   k_fused: 2048 blocks (b, ho, half-row), 4 waves; wave owns 32 outs x 32 px.
//   Per tap: 8 uniform param loads, 32 coalesced gather dwords, 8 packed blends,
//   8 LDS writes, barrier, 8 coalesced W-fragment loads (issued post-gather),
//   16 MFMA. S dbuf [2][32][68] = 17.4 KB; launch_bounds(256,6) -> 6 blocks/CU.
//   k_transpose/k_prep/k_offconv/k_params unchanged (validated R9).

typedef unsigned int u32;
typedef __attribute__((ext_vector_type(8))) _Float16 f16x8;
typedef __attribute__((ext_vector_type(4))) float f32x4;

union U16 { uint4 u; f16x8 h; };
union H2U { __half2 h2; u32 u; };

static __device__ __forceinline__ u32 pkh(float a, float b) {
    H2U c; c.h2 = __float22half2_rn(make_float2(a, b)); return c.u;
}
static __device__ __forceinline__ u32 pkw(float w) {
    __half h = __float2half_rn(w);
    H2U c; c.h2 = __half2(h, h); return c.u;
}
static __device__ __forceinline__ u32 hfma2u(u32 a, u32 w, u32 acc) {
    H2U x, y, z; x.u = a; y.u = w; z.u = acc;
    z.h2 = __hfma2(x.h2, y.h2, z.h2); return z.u;
}
static __device__ __forceinline__ u32 hmul2u(u32 a, u32 w) {
    H2U x, y; x.u = a; y.u = w;
    y.h2 = __hmul2(x.h2, y.h2); return y.u;
}

#define B_   16
#define HW_  4096
#define CU_  64          // 128 ch = 64 fp16-pair words

// ---------------- kernel 1: NCHW f32 -> NHWC fp16 ----------------
__global__ __launch_bounds__(256) void k_transpose(const float* __restrict__ x,
                                                   u32* __restrict__ xtu) {
    __shared__ float tile[32][129];
    int blk = blockIdx.x, t = threadIdx.x;
    int b = blk >> 7, hw0 = (blk & 127) << 5;
    int hwl = t & 31, cg = t >> 5;
    const float* src = x + (size_t)b * 128 * HW_ + hw0 + hwl;
#pragma unroll
    for (int i = 0; i < 16; ++i) { int c = cg + (i << 3); tile[hwl][c] = src[(size_t)c * HW_]; }
    __syncthreads();
    u32* dst = xtu + ((size_t)b * HW_ + hw0) * CU_;
    int u = t & 63, hq = t >> 6;
#pragma unroll
    for (int j = 0; j < 8; ++j) {
        int hw = (hq << 3) + j;
        dst[(size_t)hw * CU_ + u] = pkh(tile[hw][2 * u], tile[hw][2 * u + 1]);
    }
}

// ---------------- kernel 2: weight prep ----------------
__global__ __launch_bounds__(256) void k_prep(const float* __restrict__ weight,
                                              const float* __restrict__ off_w,
                                              uint4* __restrict__ wtv,
                                              u32* __restrict__ woffu) {
    int idx = blockIdx.x * 256 + threadIdx.x;
    if (idx < 18432) {
        int l = idx & 63, og = (idx >> 6) & 7, ks = (idx >> 9) & 3, n = idx >> 11;
        int o = og * 16 + (l & 15);
        int c0 = ks * 32 + (l >> 4) * 8;
        u32 r[4];
#pragma unroll
        for (int q = 0; q < 4; ++q) {
            int c = c0 + 2 * q;
            r[q] = pkh(weight[((size_t)(o * 128 + c)) * 9 + n],
                       weight[((size_t)(o * 128 + c + 1)) * 9 + n]);
        }
        wtv[idx] = make_uint4(r[0], r[1], r[2], r[3]);
    } else {
        int k = idx - 18432;
        int o = k / 576, r = k % 576;
        int tap = r / 64, cu = r % 64, c = cu * 2;
        u32 v = 0u;
        if (o < 27) {
            float a = off_w[((size_t)(o * 128 + c)) * 9 + tap];
            float b = off_w[((size_t)(o * 128 + c + 1)) * 9 + tap];
            v = pkh(a, b);
        }
        woffu[k] = v;
    }
}

// ---------------- kernel 3: offset/mask conv via MFMA ----------------
__global__ __launch_bounds__(256) void k_offconv(const u32* __restrict__ xtu,
                                                 const u32* __restrict__ woffu,
                                                 const float* __restrict__ off_b,
                                                 float* __restrict__ offout) {
    __shared__ __align__(16) u32 S[3][64][64];
    int blk = ((blockIdx.x & 7) << 7) + (blockIdx.x >> 3);   // XCD-chunked
    int t = threadIdx.x;
    int b = blk >> 6, ho = blk & 63;
    const u32* xb = xtu + (size_t)b * HW_ * CU_;
    const uint4 z4 = {0u, 0u, 0u, 0u};
#pragma unroll
    for (int i = 0; i < 12; ++i) {
        int li = t + (i << 8);
        int r = li >> 10, rem = li & 1023;
        int px = rem >> 4, ch = rem & 15;
        int yy = ho + r - 1;
        uint4 v = ((unsigned)yy < 64u) ? *(const uint4*)(xb + ((yy << 6) + px) * CU_ + (ch << 2)) : z4;
        *(uint4*)&S[r][px][(ch ^ (px & 7)) << 2] = v;
    }
    __syncthreads();
    int lane = t & 63, w = t >> 6, l15 = lane & 15, lhi = lane >> 4;
    int ob = w >> 1, pb0 = (w & 1) << 1;
    f32x4 acc[2];
    acc[0] = (f32x4){0.f, 0.f, 0.f, 0.f};
    acc[1] = (f32x4){0.f, 0.f, 0.f, 0.f};
#pragma unroll 1
    for (int tap = 0; tap < 9; ++tap) {
        int ky = tap / 3, kx = tap % 3;
        int yy = ho + ky - 1;
        if ((unsigned)yy >= 64u) continue;
        U16 af[4];
#pragma unroll
        for (int ks = 0; ks < 4; ++ks)
            af[ks].u = *(const uint4*)(woffu + (size_t)(ob * 16 + l15) * 576
                                       + tap * 64 + ks * 16 + lhi * 4);
#pragma unroll
        for (int pp = 0; pp < 2; ++pp) {
            int pr = ((pb0 + pp) << 4) + l15;
            int pxs = pr + kx - 1;
            bool v = (unsigned)pxs < 64u;
            int pxc = v ? pxs : 0;
#pragma unroll
            for (int ks = 0; ks < 4; ++ks) {
                U16 sf;
                sf.u = v ? *(const uint4*)&S[ky][pxc][((ks * 4 + lhi) ^ (pxc & 7)) << 2] : z4;
                acc[pp] = __builtin_amdgcn_mfma_f32_16x16x32_f16(af[ks].h, sf.h, acc[pp], 0, 0, 0);
            }
        }
    }
    float* dst = offout + (size_t)b * 27 * HW_ + (ho << 6);
#pragma unroll
    for (int pp = 0; pp < 2; ++pp)
#pragma unroll
        for (int r = 0; r < 4; ++r) {
            int o = ob * 16 + lhi * 4 + r;
            if (o < 27) {
                float s = acc[pp][r] + off_b[o];
                if (o >= 18) s = 1.f / (1.f + __expf(-s));
                dst[(size_t)o * HW_ + ((pb0 + pp) << 4) + l15] = s;
            }
        }
}

// ---------------- kernel 3.5: pack per-sample params ----------------
__global__ __launch_bounds__(256) void k_params(const float* __restrict__ offout,
                                                uint4* __restrict__ paramsW,
                                                uint2* __restrict__ paramsA) {
    int g = blockIdx.x * 256 + threadIdx.x;    // 589824 total
    int wo = g & 63, r = g >> 6;
    int tap = r % 9, bho = r / 9;
    int ho = bho & 63, b = bho >> 6;
    const float* ob_ = offout + (size_t)b * 27 * HW_ + ho * 64 + wo;
    float dy = ob_[(size_t)(2 * tap) * HW_];
    float dx = ob_[(size_t)(2 * tap + 1) * HW_];
    float m  = ob_[(size_t)(18 + tap) * HW_];
    float ys = (float)(ho + tap / 3 - 1) + dy;
    float xs = (float)(wo + tap % 3 - 1) + dx;
    float y0f = floorf(ys), x0f = floorf(xs);
    float fy = ys - y0f, fx = xs - x0f;
    int y0 = (int)y0f, x0 = (int)x0f;
    bool vy0 = (unsigned)y0 < 64u, vy1 = (unsigned)(y0 + 1) < 64u;
    bool vx0 = (unsigned)x0 < 64u, vx1 = (unsigned)(x0 + 1) < 64u;
    u32 w00 = pkw((vy0 && vx0) ? (1.f - fy) * (1.f - fx) * m : 0.f);
    u32 w01 = pkw((vy0 && vx1) ? (1.f - fy) * fx * m : 0.f);
    u32 w10 = pkw((vy1 && vx0) ? fy * (1.f - fx) * m : 0.f);
    u32 w11 = pkw((vy1 && vx1) ? fy * fx * m : 0.f);
    int y0c = min(max(y0, 0), 63), y1c = min(max(y0 + 1, 0), 63);
    int x0c = min(max(x0, 0), 63), x1c = min(max(x0 + 1, 0), 63);
    u32 a00 = ((u32)y0c << 14) + ((u32)x0c << 8);   // byte addrs within batch slice
    u32 a11 = ((u32)y1c << 14) + ((u32)x1c << 8);
    paramsW[g] = make_uint4(w00, w01, w10, w11);
    paramsA[g] = make_uint2(a00, a11);
}

// ---------------- kernel 4: fused sample + MFMA, 32-px blocks ----------------
__global__ __launch_bounds__(256, 6) void k_fused(const u32* __restrict__ xtu,
                                                  const uint4* __restrict__ wtv,
                                                  const uint4* __restrict__ paramsW,
                                                  const uint2* __restrict__ paramsA,
                                                  const float* __restrict__ bias,
                                                  float* __restrict__ out) {
    __shared__ __align__(16) u32 S[2][32][68];   // dbuf, 17.4 KB
    int raw = blockIdx.x;
    int blk = ((raw & 7) << 8) + (raw >> 3);     // XCD-chunked, 2048 = 8*256
    int t = threadIdx.x;
    int b = blk >> 7, rem = blk & 127;
    int ho = rem >> 1, px0 = (rem & 1) << 5;
    int w = t >> 6, lane = t & 63, l15 = lane & 15, lhi = lane >> 4;
    int o0 = w * 32;
    int lane4 = lane << 2;

    f32x4 acc[2][2];
#pragma unroll
    for (int ob = 0; ob < 2; ++ob)
#pragma unroll
        for (int pb = 0; pb < 2; ++pb) acc[ob][pb] = (f32x4){0.f, 0.f, 0.f, 0.f};

    const char* xbb = (const char*)(xtu + (size_t)b * HW_ * CU_);
    int pbase = ((b << 6) + ho) * 9;
    const uint4* pWb = paramsW + (size_t)pbase * 64 + px0 + (w << 3);
    const uint2* pAb = paramsA + (size_t)pbase * 64 + px0 + (w << 3);

#pragma unroll 1
    for (int n = 0; n < 9; ++n) {
        const uint4* pW = pWb + n * 64;
        const uint2* pA = pAb + n * 64;
        int buf = n & 1;
        // --- gather + blend: this wave's 8 px ---
        u32 ld[8][4];
#pragma unroll
        for (int j = 0; j < 8; ++j) {
            uint2 aa = pA[j];                   // wave-uniform 8B load
            u32 a00 = aa.x, a11 = aa.y;
            u32 a01 = (a00 & ~0x3FFFu) | (a11 & 0x3FFFu);
            u32 a10 = (a11 & ~0x3FFFu) | (a00 & 0x3FFFu);
            ld[j][0] = *(const u32*)(xbb + a00 + lane4);
            ld[j][1] = *(const u32*)(xbb + a01 + lane4);
            ld[j][2] = *(const u32*)(xbb + a10 + lane4);
            ld[j][3] = *(const u32*)(xbb + a11 + lane4);
        }
#pragma unroll
        for (int j = 0; j < 8; ++j) {
            uint4 ww = pW[j];                   // wave-uniform 16B load
            u32 r = hfma2u(ld[j][3], ww.w, hfma2u(ld[j][2], ww.z,
                    hfma2u(ld[j][1], ww.y, hmul2u(ld[j][0], ww.x))));
            S[buf][(w << 3) + j][lane] = r;
        }
        // --- W fragments (issued after gather so ld regs retire first) ---
        U16 wf[2][4];
#pragma unroll
        for (int ob = 0; ob < 2; ++ob)
#pragma unroll
            for (int ks = 0; ks < 4; ++ks)
                wf[ob][ks].u = wtv[(((n << 2) + ks) * 8 + (w << 1) + ob) * 64 + lane];
        __syncthreads();
        // --- MFMA: D[o][px] += W_tap * S_tap^T ---
#pragma unroll
        for (int ks = 0; ks < 4; ++ks) {
            U16 sf[2];
#pragma unroll
            for (int pb = 0; pb < 2; ++pb)
                sf[pb].u = *(const uint4*)&S[buf][pb * 16 + l15][(ks * 4 + lhi) << 2];
#pragma unroll
            for (int ob = 0; ob < 2; ++ob)
#pragma unroll
                for (int pb = 0; pb < 2; ++pb)
                    acc[ob][pb] = __builtin_amdgcn_mfma_f32_16x16x32_f16(
                        wf[ob][ks].h, sf[pb].h, acc[ob][pb], 0, 0, 0);
        }
    }
    // --- epilogue: o = o0+ob*16+lhi*4+r, px = px0+pb*16+l15 ---
    float* ob_base = out + (size_t)b * 128 * HW_ + ho * 64 + px0;
#pragma unroll
    for (int ob = 0; ob < 2; ++ob)
#pragma unroll
        for (int r = 0; r < 4; ++r) {
            int o = o0 + ob * 16 + lhi * 4 + r;
            float bv = bias[o];
#pragma unroll
            for (int pb = 0; pb < 2; ++pb)
                ob_base[(size_t)o * HW_ + pb * 16 + l15] = acc[ob][pb][r] + bv;
        }
}

extern "C" void kernel_launch(void* const* d_in, const int* in_sizes, int n_in,
                              void* d_out, int out_size, void* d_ws, size_t ws_size,
                              hipStream_t stream) {
    const float* x      = (const float*)d_in[0];
    const float* weight = (const float*)d_in[1];
    const float* bias   = (const float*)d_in[2];
    const float* off_w  = (const float*)d_in[3];
    const float* off_b  = (const float*)d_in[4];
    float* out = (float*)d_out;

    // ws (u32 units): xtu 4194304 | offout 1769472 | wtv 73728 | woffu 18432
    //                 | paramsW 2359296 | paramsA 1179648   -> 38.4 MB
    u32*   xtu     = (u32*)d_ws;
    float* offout  = (float*)(xtu + (size_t)B_ * HW_ * CU_);
    uint4* wtv     = (uint4*)(offout + (size_t)B_ * 27 * HW_);
    u32*   woffu   = (u32*)wtv + 73728;
    uint4* paramsW = (uint4*)(woffu + 18432);
    uint2* paramsA = (uint2*)((u32*)paramsW + 2359296);

    hipLaunchKernelGGL(k_transpose, dim3(2048), dim3(256), 0, stream, x, xtu);
    hipLaunchKernelGGL(k_prep, dim3(144), dim3(256), 0, stream, weight, off_w, wtv, woffu);
    hipLaunchKernelGGL(k_offconv, dim3(1024), dim3(256), 0, stream, xtu, woffu, off_b, offout);
    hipLaunchKernelGGL(k_params, dim3(2304), dim3(256), 0, stream, offout, paramsW, paramsA);
    hipLaunchKernelGGL(k_fused, dim3(2048), dim3(256), 0, stream, xtu, wtv, paramsW, paramsA, bias, out);
}

// Round 11
// 108.994 us; speedup vs baseline: 1.1899x; 1.1899x over previous
//
#include <hip/hip_runtime.h>
#include <hip/hip_fp16.h>

// DCNv2 R11: counted-vmcnt pipeline across raw s_barrier in k_fused.
//   Per tap n: [load pr(n+2) early] blend(n) from PRM weights + ld regs ->
//   S[n&1]; load W(n) frags; ds_write pr; issue G(n+1) (64 gathers, fly
//   ACROSS the barrier); lgkmcnt(0)+s_barrier (NO vmcnt drain!); MFMA(n).
//   Params packed by k_params as uint4 {w00|w01, w10|w11, a00, a11} and
//   staged per-wave into LDS (load-early/write-late). W(n) issued before
//   G(n+1) so in-order vmcnt waits on wf never drain the gather queue.

typedef unsigned int u32;
typedef __attribute__((ext_vector_type(8))) _Float16 f16x8;
typedef __attribute__((ext_vector_type(4))) float f32x4;

union U16 { uint4 u; f16x8 h; };
union H2U { __half2 h2; u32 u; };

static __device__ __forceinline__ u32 pkh(float a, float b) {
    H2U c; c.h2 = __float22half2_rn(make_float2(a, b)); return c.u;
}
static __device__ __forceinline__ u32 h1(float f) {
    return (u32)__half_as_ushort(__float2half_rn(f));
}
static __device__ __forceinline__ u32 hfma2u(u32 a, u32 w, u32 acc) {
    H2U x, y, z; x.u = a; y.u = w; z.u = acc;
    z.h2 = __hfma2(x.h2, y.h2, z.h2); return z.u;
}
static __device__ __forceinline__ u32 hmul2u(u32 a, u32 w) {
    H2U x, y; x.u = a; y.u = w;
    y.h2 = __hmul2(x.h2, y.h2); return y.u;
}

#define B_   16
#define HW_  4096
#define CU_  64          // 128 ch = 64 fp16-pair words

// ---------------- kernel 1: NCHW f32 -> NHWC fp16 ----------------
__global__ __launch_bounds__(256) void k_transpose(const float* __restrict__ x,
                                                   u32* __restrict__ xtu) {
    __shared__ float tile[32][129];
    int blk = blockIdx.x, t = threadIdx.x;
    int b = blk >> 7, hw0 = (blk & 127) << 5;
    int hwl = t & 31, cg = t >> 5;
    const float* src = x + (size_t)b * 128 * HW_ + hw0 + hwl;
#pragma unroll
    for (int i = 0; i < 16; ++i) { int c = cg + (i << 3); tile[hwl][c] = src[(size_t)c * HW_]; }
    __syncthreads();
    u32* dst = xtu + ((size_t)b * HW_ + hw0) * CU_;
    int u = t & 63, hq = t >> 6;
#pragma unroll
    for (int j = 0; j < 8; ++j) {
        int hw = (hq << 3) + j;
        dst[(size_t)hw * CU_ + u] = pkh(tile[hw][2 * u], tile[hw][2 * u + 1]);
    }
}

// ---------------- kernel 2: weight prep ----------------
__global__ __launch_bounds__(256) void k_prep(const float* __restrict__ weight,
                                              const float* __restrict__ off_w,
                                              uint4* __restrict__ wtv,
                                              u32* __restrict__ woffu) {
    int idx = blockIdx.x * 256 + threadIdx.x;
    if (idx < 18432) {
        int l = idx & 63, og = (idx >> 6) & 7, ks = (idx >> 9) & 3, n = idx >> 11;
        int o = og * 16 + (l & 15);
        int c0 = ks * 32 + (l >> 4) * 8;
        u32 r[4];
#pragma unroll
        for (int q = 0; q < 4; ++q) {
            int c = c0 + 2 * q;
            r[q] = pkh(weight[((size_t)(o * 128 + c)) * 9 + n],
                       weight[((size_t)(o * 128 + c + 1)) * 9 + n]);
        }
        wtv[idx] = make_uint4(r[0], r[1], r[2], r[3]);
    } else {
        int k = idx - 18432;
        int o = k / 576, r = k % 576;
        int tap = r / 64, cu = r % 64, c = cu * 2;
        u32 v = 0u;
        if (o < 27) {
            float a = off_w[((size_t)(o * 128 + c)) * 9 + tap];
            float b = off_w[((size_t)(o * 128 + c + 1)) * 9 + tap];
            v = pkh(a, b);
        }
        woffu[k] = v;
    }
}

// ---------------- kernel 3: offset/mask conv via MFMA ----------------
__global__ __launch_bounds__(256) void k_offconv(const u32* __restrict__ xtu,
                                                 const u32* __restrict__ woffu,
                                                 const float* __restrict__ off_b,
                                                 float* __restrict__ offout) {
    __shared__ __align__(16) u32 S[3][64][64];
    int blk = ((blockIdx.x & 7) << 7) + (blockIdx.x >> 3);   // XCD-chunked
    int t = threadIdx.x;
    int b = blk >> 6, ho = blk & 63;
    const u32* xb = xtu + (size_t)b * HW_ * CU_;
    const uint4 z4 = {0u, 0u, 0u, 0u};
#pragma unroll
    for (int i = 0; i < 12; ++i) {
        int li = t + (i << 8);
        int r = li >> 10, rem = li & 1023;
        int px = rem >> 4, ch = rem & 15;
        int yy = ho + r - 1;
        uint4 v = ((unsigned)yy < 64u) ? *(const uint4*)(xb + ((yy << 6) + px) * CU_ + (ch << 2)) : z4;
        *(uint4*)&S[r][px][(ch ^ (px & 7)) << 2] = v;
    }
    __syncthreads();
    int lane = t & 63, w = t >> 6, l15 = lane & 15, lhi = lane >> 4;
    int ob = w >> 1, pb0 = (w & 1) << 1;
    f32x4 acc[2];
    acc[0] = (f32x4){0.f, 0.f, 0.f, 0.f};
    acc[1] = (f32x4){0.f, 0.f, 0.f, 0.f};
#pragma unroll 1
    for (int tap = 0; tap < 9; ++tap) {
        int ky = tap / 3, kx = tap % 3;
        int yy = ho + ky - 1;
        if ((unsigned)yy >= 64u) continue;
        U16 af[4];
#pragma unroll
        for (int ks = 0; ks < 4; ++ks)
            af[ks].u = *(const uint4*)(woffu + (size_t)(ob * 16 + l15) * 576
                                       + tap * 64 + ks * 16 + lhi * 4);
#pragma unroll
        for (int pp = 0; pp < 2; ++pp) {
            int pr = ((pb0 + pp) << 4) + l15;
            int pxs = pr + kx - 1;
            bool v = (unsigned)pxs < 64u;
            int pxc = v ? pxs : 0;
#pragma unroll
            for (int ks = 0; ks < 4; ++ks) {
                U16 sf;
                sf.u = v ? *(const uint4*)&S[ky][pxc][((ks * 4 + lhi) ^ (pxc & 7)) << 2] : z4;
                acc[pp] = __builtin_amdgcn_mfma_f32_16x16x32_f16(af[ks].h, sf.h, acc[pp], 0, 0, 0);
            }
        }
    }
    float* dst = offout + (size_t)b * 27 * HW_ + (ho << 6);
#pragma unroll
    for (int pp = 0; pp < 2; ++pp)
#pragma unroll
        for (int r = 0; r < 4; ++r) {
            int o = ob * 16 + lhi * 4 + r;
            if (o < 27) {
                float s = acc[pp][r] + off_b[o];
                if (o >= 18) s = 1.f / (1.f + __expf(-s));
                dst[(size_t)o * HW_ + ((pb0 + pp) << 4) + l15] = s;
            }
        }
}

// ---------------- kernel 3.5: pack per-sample params (one uint4) ----------------
__global__ __launch_bounds__(256) void k_params(const float* __restrict__ offout,
                                                uint4* __restrict__ params) {
    int g = blockIdx.x * 256 + threadIdx.x;    // 589824 total
    int wo = g & 63, r = g >> 6;
    int tap = r % 9, bho = r / 9;
    int ho = bho & 63, b = bho >> 6;
    const float* ob_ = offout + (size_t)b * 27 * HW_ + ho * 64 + wo;
    float dy = ob_[(size_t)(2 * tap) * HW_];
    float dx = ob_[(size_t)(2 * tap + 1) * HW_];
    float m  = ob_[(size_t)(18 + tap) * HW_];
    float ys = (float)(ho + tap / 3 - 1) + dy;
    float xs = (float)(wo + tap % 3 - 1) + dx;
    float y0f = floorf(ys), x0f = floorf(xs);
    float fy = ys - y0f, fx = xs - x0f;
    int y0 = (int)y0f, x0 = (int)x0f;
    bool vy0 = (unsigned)y0 < 64u, vy1 = (unsigned)(y0 + 1) < 64u;
    bool vx0 = (unsigned)x0 < 64u, vx1 = (unsigned)(x0 + 1) < 64u;
    u32 h00 = h1((vy0 && vx0) ? (1.f - fy) * (1.f - fx) * m : 0.f);
    u32 h01 = h1((vy0 && vx1) ? (1.f - fy) * fx * m : 0.f);
    u32 h10 = h1((vy1 && vx0) ? fy * (1.f - fx) * m : 0.f);
    u32 h11 = h1((vy1 && vx1) ? fy * fx * m : 0.f);
    int y0c = min(max(y0, 0), 63), y1c = min(max(y0 + 1, 0), 63);
    int x0c = min(max(x0, 0), 63), x1c = min(max(x0 + 1, 0), 63);
    u32 a00 = ((u32)y0c << 14) + ((u32)x0c << 8);   // byte addr within batch slice
    u32 a11 = ((u32)y1c << 14) + ((u32)x1c << 8);
    params[g] = make_uint4(h00 | (h01 << 16), h10 | (h11 << 16), a00, a11);
}

// ---------------- kernel 4: fused sample + MFMA, pipelined raw barrier ----------
__global__ __launch_bounds__(256, 3) void k_fused(const u32* __restrict__ xtu,
                                                  const uint4* __restrict__ wtv,
                                                  const u32* __restrict__ paramsU,
                                                  const float* __restrict__ bias,
                                                  float* __restrict__ out) {
    __shared__ __align__(16) u32 S[2][64][68];   // dbuf, 34.8 KB
    __shared__ __align__(16) u32 PRM[2][256];    // per-wave param slices, 2 KB
    int blk = ((blockIdx.x & 7) << 7) + (blockIdx.x >> 3);   // XCD-chunked
    int t = threadIdx.x;
    int b = blk >> 6, ho = blk & 63;
    int w = t >> 6, lane = t & 63, l15 = lane & 15, lhi = lane >> 4;
    int o0 = w * 32;
    int lane4 = lane << 2;
    int wbase = w << 6;

    f32x4 acc[2][4];
#pragma unroll
    for (int ob = 0; ob < 2; ++ob)
#pragma unroll
        for (int pb = 0; pb < 4; ++pb) acc[ob][pb] = (f32x4){0.f, 0.f, 0.f, 0.f};

    const char* xbb = (const char*)(xtu + (size_t)b * HW_ * CU_);
    int pbase = ((b << 6) + ho) * 9;
    const u32* pU = paramsU + (size_t)pbase * 256 + wbase + lane;

    u32 ld[16][4];

#define ISSUE_G(NB)                                                          \
    _Pragma("unroll") for (int j = 0; j < 16; ++j) {                         \
        uint2 av = *(const uint2*)&PRM[NB][wbase + (j << 2) + 2];            \
        u32 a00 = av.x, a11 = av.y;                                          \
        u32 a01 = (a00 & ~0x3FFFu) | (a11 & 0x3FFFu);                        \
        u32 a10 = (a11 & ~0x3FFFu) | (a00 & 0x3FFFu);                        \
        ld[j][0] = *(const u32*)(xbb + a00 + lane4);                         \
        ld[j][1] = *(const u32*)(xbb + a01 + lane4);                         \
        ld[j][2] = *(const u32*)(xbb + a10 + lane4);                         \
        ld[j][3] = *(const u32*)(xbb + a11 + lane4);                         \
    }

    // --- prologue: stage params(0), params(1); issue G(0) ---
    {
        u32 p0 = pU[0];
        u32 p1 = pU[256];
        PRM[0][wbase + lane] = p0;
        PRM[1][wbase + lane] = p1;
    }
    ISSUE_G(0);

#pragma unroll 1
    for (int n = 0; n < 9; ++n) {
        int buf = n & 1;
        // --- prefetch params(n+2) (load early, write late: T14) ---
        u32 pr = 0u;
        if (n < 7) pr = pU[(size_t)(n + 2) * 256];
        // --- blend(n): weights from PRM[buf], data from ld (auto vmcnt) ---
#pragma unroll
        for (int j = 0; j < 16; ++j) {
            uint2 wv = *(const uint2*)&PRM[buf][wbase + (j << 2)];
            u32 lo  = wv.x & 0xFFFFu; u32 w00p = lo  | (lo  << 16);
            u32 hi  = wv.x >> 16;     u32 w01p = hi  | (hi  << 16);
            u32 lo2 = wv.y & 0xFFFFu; u32 w10p = lo2 | (lo2 << 16);
            u32 hi2 = wv.y >> 16;     u32 w11p = hi2 | (hi2 << 16);
            u32 r = hfma2u(ld[j][3], w11p, hfma2u(ld[j][2], w10p,
                    hfma2u(ld[j][1], w01p, hmul2u(ld[j][0], w00p))));
            S[buf][(w << 4) + j][lane] = r;
        }
        // --- W(n) fragments: issued BEFORE G(n+1) so wf's vmcnt wait
        //     (in-order) never drains the gather queue ---
        U16 wf[2][4];
#pragma unroll
        for (int ob = 0; ob < 2; ++ob)
#pragma unroll
            for (int ks = 0; ks < 4; ++ks)
                wf[ob][ks].u = wtv[(((n << 2) + ks) * 8 + (w << 1) + ob) * 64 + lane];
        // --- write params(n+2) slice; issue G(n+1): flies across barrier ---
        if (n < 7) PRM[buf][wbase + lane] = pr;
        if (n < 8) { ISSUE_G((n + 1) & 1); }
        // --- raw barrier: LDS drained, vmem stays in flight ---
        asm volatile("s_waitcnt lgkmcnt(0)" ::: "memory");
        __builtin_amdgcn_sched_barrier(0);
        __builtin_amdgcn_s_barrier();
        __builtin_amdgcn_sched_barrier(0);
        // --- MFMA(n): D[o][px] += W_tap * S_tap^T ---
#pragma unroll
        for (int ks = 0; ks < 4; ++ks) {
            U16 sf[4];
#pragma unroll
            for (int pb = 0; pb < 4; ++pb)
                sf[pb].u = *(const uint4*)&S[buf][pb * 16 + l15][(ks * 4 + lhi) << 2];
#pragma unroll
            for (int ob = 0; ob < 2; ++ob)
#pragma unroll
                for (int pb = 0; pb < 4; ++pb)
                    acc[ob][pb] = __builtin_amdgcn_mfma_f32_16x16x32_f16(
                        wf[ob][ks].h, sf[pb].h, acc[ob][pb], 0, 0, 0);
        }
    }
#undef ISSUE_G
    // --- epilogue: o = o0+ob*16+lhi*4+r, px = pb*16+l15 ---
    float* ob_base = out + (size_t)b * 128 * HW_ + ho * 64;
#pragma unroll
    for (int ob = 0; ob < 2; ++ob)
#pragma unroll
        for (int r = 0; r < 4; ++r) {
            int o = o0 + ob * 16 + lhi * 4 + r;
            float bv = bias[o];
#pragma unroll
            for (int pb = 0; pb < 4; ++pb)
                ob_base[(size_t)o * HW_ + pb * 16 + l15] = acc[ob][pb][r] + bv;
        }
}

extern "C" void kernel_launch(void* const* d_in, const int* in_sizes, int n_in,
                              void* d_out, int out_size, void* d_ws, size_t ws_size,
                              hipStream_t stream) {
    const float* x      = (const float*)d_in[0];
    const float* weight = (const float*)d_in[1];
    const float* bias   = (const float*)d_in[2];
    const float* off_w  = (const float*)d_in[3];
    const float* off_b  = (const float*)d_in[4];
    float* out = (float*)d_out;

    // ws (u32 units): xtu 4194304 | offout 1769472 | wtv 294912 | woffu 18432
    //                 | params 2359296   -> ~34.5 MB
    u32*   xtu    = (u32*)d_ws;
    float* offout = (float*)(xtu + (size_t)B_ * HW_ * CU_);
    uint4* wtv    = (uint4*)(offout + (size_t)B_ * 27 * HW_);
    u32*   woffu  = (u32*)wtv + 294912;
    uint4* params = (uint4*)(woffu + 18432);

    hipLaunchKernelGGL(k_transpose, dim3(2048), dim3(256), 0, stream, x, xtu);
    hipLaunchKernelGGL(k_prep, dim3(144), dim3(256), 0, stream, weight, off_w, wtv, woffu);
    hipLaunchKernelGGL(k_offconv, dim3(1024), dim3(256), 0, stream, xtu, woffu, off_b, offout);
    hipLaunchKernelGGL(k_params, dim3(2304), dim3(256), 0, stream, offout, params);
    hipLaunchKernelGGL(k_fused, dim3(1024), dim3(256), 0, stream, xtu, wtv, (const u32*)params, bias, out);
}